// Round 2
// baseline (102.877 us; speedup 1.0000x reference)
//
#include <hip/hip_runtime.h>
#include <math.h>

#define BB   8
#define IND  128
#define OUTD 128
#define NN   256
#define NQ   64          // NN/4 float4 quads
#define BN_EPS 1e-5f

// Grid: 128 blocks (one per channel c). Block: (64, 8) = 512 threads.
//   threadIdx.y = batch b  -> each batch is exactly one wave64:
//                             S2/SV reductions are pure wave shuffles.
//   threadIdx.x = n-quad   -> float4 loads/stores (16B/lane, coalesced 1KB/wave).
// BatchNorm stats over (B,N)=2048 remain block-local (8-wave LDS combine).
__global__ __launch_bounds__(512) void layer1dpe_fused(
    const float* __restrict__ A,    // [B, IND, NN]
    const float* __restrict__ P1,   // [OUTD, IND]
    const float* __restrict__ P2,   // [OUTD, IND]
    const float* __restrict__ kw,   // [OUTD, IND]
    const float* __restrict__ gamma,// [OUTD]
    const float* __restrict__ beta, // [OUTD]
    float* __restrict__ out)        // [B, OUTD, NN]
{
    const int c    = blockIdx.x;
    const int x    = threadIdx.x;   // n-quad, 0..63  (= lane)
    const int b    = threadIdx.y;   // batch = wave id, 0..7

    __shared__ float w1[IND], w2[IND], wk[IND];
    {
        const int tid = b * 64 + x;
        if (tid < IND) {
            w1[tid] = P1[c * IND + tid];
            w2[tid] = P2[c * IND + tid];
            wk[tid] = kw[c * IND + tid];
        }
    }
    __syncthreads();

    const float4* __restrict__ A4 = (const float4*)A;
    // A4 index: (b*IND + i)*NQ + x
    float a1[4], vv[4], kv[4];
    #pragma unroll
    for (int j = 0; j < 4; ++j) { a1[j] = 0.f; vv[j] = 0.f; kv[j] = 0.f; }

    #pragma unroll 8
    for (int i = 0; i < IND; ++i) {
        const float4 a = A4[(b * IND + i) * NQ + x];
        const float wa = w1[i], wb = w2[i], wc = wk[i];
        a1[0] = fmaf(wa, a.x, a1[0]); a1[1] = fmaf(wa, a.y, a1[1]);
        a1[2] = fmaf(wa, a.z, a1[2]); a1[3] = fmaf(wa, a.w, a1[3]);
        vv[0] = fmaf(wb, a.x, vv[0]); vv[1] = fmaf(wb, a.y, vv[1]);
        vv[2] = fmaf(wb, a.z, vv[2]); vv[3] = fmaf(wb, a.w, vv[3]);
        kv[0] = fmaf(wc, a.x, kv[0]); kv[1] = fmaf(wc, a.y, kv[1]);
        kv[2] = fmaf(wc, a.z, kv[2]); kv[3] = fmaf(wc, a.w, kv[3]);
    }

    // Per-batch reductions: S2 = sum_n kv^2, SV = sum_n |kv|*vv.
    // Batch == wave, so this is a pure 64-lane butterfly.
    float s2 = 0.f, sv = 0.f;
    #pragma unroll
    for (int j = 0; j < 4; ++j) {
        s2 = fmaf(kv[j], kv[j], s2);
        sv = fmaf(fabsf(kv[j]), vv[j], sv);
    }
    #pragma unroll
    for (int off = 32; off >= 1; off >>= 1) {
        s2 += __shfl_xor(s2, off, 64);
        sv += __shfl_xor(sv, off, 64);
    }
    const float y = sv / sqrtf(s2);   // Y[b,c,i] == SV/||K||, independent of i

    float p[4];
    float bnsum = 0.f, bnsq = 0.f;
    #pragma unroll
    for (int j = 0; j < 4; ++j) {
        float t = a1[j] + vv[j] + 0.1f * y;
        t = fmaxf(t, 0.f);            // ReLU
        p[j] = t;
        bnsum += t;
        bnsq  = fmaf(t, t, bnsq);
    }

    // Block-wide BatchNorm stats over (B,N) = 2048 elements.
    #pragma unroll
    for (int off = 32; off >= 1; off >>= 1) {
        bnsum += __shfl_xor(bnsum, off, 64);
        bnsq  += __shfl_xor(bnsq,  off, 64);
    }
    __shared__ float red[BB][2];
    if (x == 0) { red[b][0] = bnsum; red[b][1] = bnsq; }
    __syncthreads();
    float tsum = 0.f, tsq = 0.f;
    #pragma unroll
    for (int w = 0; w < BB; ++w) { tsum += red[w][0]; tsq += red[w][1]; }

    const float inv   = 1.f / (float)(BB * NN);
    const float mean  = tsum * inv;
    const float var   = tsq * inv - mean * mean;   // biased var, matches jnp.var
    const float scale = gamma[c] * rsqrtf(var + BN_EPS);
    const float shift = beta[c] - mean * scale;

    float4* __restrict__ out4 = (float4*)out;
    out4[(b * OUTD + c) * NQ + x] = make_float4(
        fmaf(p[0], scale, shift), fmaf(p[1], scale, shift),
        fmaf(p[2], scale, shift), fmaf(p[3], scale, shift));
}

extern "C" void kernel_launch(void* const* d_in, const int* in_sizes, int n_in,
                              void* d_out, int out_size, void* d_ws, size_t ws_size,
                              hipStream_t stream) {
    // setup_inputs order: A, P1, P2, q, k, gamma, beta, permutation_size1, BATCH_SIZE
    const float* A     = (const float*)d_in[0];
    const float* P1    = (const float*)d_in[1];
    const float* P2    = (const float*)d_in[2];
    // d_in[3] = q : unused (cancels in Alpha_norm)
    const float* kw    = (const float*)d_in[4];
    const float* gamma = (const float*)d_in[5];
    const float* beta  = (const float*)d_in[6];
    float* out = (float*)d_out;

    dim3 block(64, 8);
    layer1dpe_fused<<<OUTD, block, 0, stream>>>(A, P1, P2, kw, gamma, beta, out);
}

// Round 3
// 79.630 us; speedup vs baseline: 1.2919x; 1.2919x over previous
//
#include <hip/hip_runtime.h>
#include <math.h>

#define BB   8
#define IND  128
#define OUTD 128
#define NN   256
#define NQ   64          // NN/4 float4 quads
#define BN_EPS 1e-5f
#define PSTR 13          // partial-buffer stride (12 values + 1 pad -> conflict-free)

// Grid: 128 blocks (one per channel c). Block: (64, 8, 2) = 1024 threads = 16 waves.
//   threadIdx.x = n-quad (lane), threadIdx.y = batch b (wave id within z-slice),
//   threadIdx.z = i-half (splits the K=128 contraction for 2x wave parallelism).
// Inner loop issues 8 independent float4 loads per batch before any FMA ->
// guarantees >=8 loads in flight (R2's VGPR=28 schedule had ~2).
__global__ __launch_bounds__(1024) void layer1dpe_fused(
    const float* __restrict__ A,    // [B, IND, NN]
    const float* __restrict__ P1,   // [OUTD, IND]
    const float* __restrict__ P2,   // [OUTD, IND]
    const float* __restrict__ kw,   // [OUTD, IND]
    const float* __restrict__ gamma,// [OUTD]
    const float* __restrict__ beta, // [OUTD]
    float* __restrict__ out)        // [B, OUTD, NN]
{
    const int c = blockIdx.x;
    const int x = threadIdx.x;   // 0..63 (lane)
    const int b = threadIdx.y;   // 0..7
    const int z = threadIdx.z;   // 0..1

    __shared__ float w1[IND], w2[IND], wk[IND];
    __shared__ float part[BB][NQ][PSTR];   // z=1 partials: 12 used, pad to 13
    __shared__ float red[BB][2];

    {
        const int tid = (z * BB + b) * 64 + x;     // 0..1023
        if (tid < 128)      w1[tid]       = P1[c * IND + tid];
        else if (tid < 256) w2[tid - 128] = P2[c * IND + tid - 128];
        else if (tid < 384) wk[tid - 256] = kw[c * IND + tid - 256];
    }
    __syncthreads();

    const float4* __restrict__ A4 = (const float4*)A;
    float a1[4], vv[4], kv[4];
    #pragma unroll
    for (int j = 0; j < 4; ++j) { a1[j] = 0.f; vv[j] = 0.f; kv[j] = 0.f; }

    // This thread's i-range: [z*64, z*64+64), 8 batches of 8.
    const int ibase = z * 64;
    #pragma unroll
    for (int blk = 0; blk < 8; ++blk) {
        float4 cur[8];
        #pragma unroll
        for (int j = 0; j < 8; ++j)
            cur[j] = A4[(b * IND + ibase + blk * 8 + j) * NQ + x];
        #pragma unroll
        for (int j = 0; j < 8; ++j) {
            const int iw = ibase + blk * 8 + j;
            const float wa = w1[iw], wb = w2[iw], wc = wk[iw];
            a1[0] = fmaf(wa, cur[j].x, a1[0]); a1[1] = fmaf(wa, cur[j].y, a1[1]);
            a1[2] = fmaf(wa, cur[j].z, a1[2]); a1[3] = fmaf(wa, cur[j].w, a1[3]);
            vv[0] = fmaf(wb, cur[j].x, vv[0]); vv[1] = fmaf(wb, cur[j].y, vv[1]);
            vv[2] = fmaf(wb, cur[j].z, vv[2]); vv[3] = fmaf(wb, cur[j].w, vv[3]);
            kv[0] = fmaf(wc, cur[j].x, kv[0]); kv[1] = fmaf(wc, cur[j].y, kv[1]);
            kv[2] = fmaf(wc, cur[j].z, kv[2]); kv[3] = fmaf(wc, cur[j].w, kv[3]);
        }
    }

    // Combine the two i-halves through LDS (z=1 -> z=0).
    if (z == 1) {
        #pragma unroll
        for (int j = 0; j < 4; ++j) {
            part[b][x][j]     = a1[j];
            part[b][x][4 + j] = vv[j];
            part[b][x][8 + j] = kv[j];
        }
    }
    __syncthreads();

    float p[4];
    float bnsum = 0.f, bnsq = 0.f;
    if (z == 0) {
        #pragma unroll
        for (int j = 0; j < 4; ++j) {
            a1[j] += part[b][x][j];
            vv[j] += part[b][x][4 + j];
            kv[j] += part[b][x][8 + j];
        }
        // Per-batch reductions (batch == one wave): S2 = sum kv^2, SV = sum |kv|*vv.
        float s2 = 0.f, sv = 0.f;
        #pragma unroll
        for (int j = 0; j < 4; ++j) {
            s2 = fmaf(kv[j], kv[j], s2);
            sv = fmaf(fabsf(kv[j]), vv[j], sv);
        }
        #pragma unroll
        for (int off = 32; off >= 1; off >>= 1) {
            s2 += __shfl_xor(s2, off, 64);
            sv += __shfl_xor(sv, off, 64);
        }
        const float y = sv / sqrtf(s2);   // Y[b,c,i] independent of i; Q cancels.

        #pragma unroll
        for (int j = 0; j < 4; ++j) {
            float t = a1[j] + vv[j] + 0.1f * y;
            t = fmaxf(t, 0.f);            // ReLU
            p[j] = t;
            bnsum += t;
            bnsq  = fmaf(t, t, bnsq);
        }
        #pragma unroll
        for (int off = 32; off >= 1; off >>= 1) {
            bnsum += __shfl_xor(bnsum, off, 64);
            bnsq  += __shfl_xor(bnsq,  off, 64);
        }
        if (x == 0) { red[b][0] = bnsum; red[b][1] = bnsq; }
    }
    __syncthreads();

    if (z == 0) {
        float tsum = 0.f, tsq = 0.f;
        #pragma unroll
        for (int w = 0; w < BB; ++w) { tsum += red[w][0]; tsq += red[w][1]; }

        const float inv   = 1.f / (float)(BB * NN);
        const float mean  = tsum * inv;
        const float var   = tsq * inv - mean * mean;   // biased var, matches jnp.var
        const float scale = gamma[c] * rsqrtf(var + BN_EPS);
        const float shift = beta[c] - mean * scale;

        float4* __restrict__ out4 = (float4*)out;
        out4[(b * OUTD + c) * NQ + x] = make_float4(
            fmaf(p[0], scale, shift), fmaf(p[1], scale, shift),
            fmaf(p[2], scale, shift), fmaf(p[3], scale, shift));
    }
}

extern "C" void kernel_launch(void* const* d_in, const int* in_sizes, int n_in,
                              void* d_out, int out_size, void* d_ws, size_t ws_size,
                              hipStream_t stream) {
    // setup_inputs order: A, P1, P2, q, k, gamma, beta, permutation_size1, BATCH_SIZE
    const float* A     = (const float*)d_in[0];
    const float* P1    = (const float*)d_in[1];
    const float* P2    = (const float*)d_in[2];
    // d_in[3] = q : unused (cancels in Alpha_norm)
    const float* kw    = (const float*)d_in[4];
    const float* gamma = (const float*)d_in[5];
    const float* beta  = (const float*)d_in[6];
    float* out = (float*)d_out;

    dim3 block(64, 8, 2);
    layer1dpe_fused<<<OUTD, block, 0, stream>>>(A, P1, P2, kw, gamma, beta, out);
}

// Round 4
// 77.879 us; speedup vs baseline: 1.3210x; 1.0225x over previous
//
#include <hip/hip_runtime.h>
#include <math.h>

#define BB   8
#define IND  128
#define OUTD 128
#define NN   256
#define NQ   64          // NN/4 float4 quads
#define BN_EPS 1e-5f

// ---------------- Kernel 1: projections + Y + ReLU + BN partials ------------
// Grid (128 c, 8 b), block = 64 threads = ONE wave spanning all of n.
//  -> S2/SV reduction and BN partial sums are pure wave butterflies: no LDS,
//     no __syncthreads. 1024 small blocks pack all 256 CUs (~0.5 MB A / CU).
// Weight indices (c, i) are wave-uniform -> scalar s_load path, zero LDS.
__global__ __launch_bounds__(64) void k1_proj(
    const float* __restrict__ A,    // [B, IND, NN]
    const float* __restrict__ P1,   // [OUTD, IND]
    const float* __restrict__ P2,   // [OUTD, IND]
    const float* __restrict__ kw,   // [OUTD, IND]
    float* __restrict__ pbuf,       // ws: [B, OUTD, NN] post-ReLU pre-BN
    float* __restrict__ bnp)        // ws: [2][OUTD][BB] {sum, sumsq}
{
    const int c = blockIdx.x;
    const int b = blockIdx.y;
    const int x = threadIdx.x;      // lane 0..63 = n-quad

    const float4* __restrict__ A4 = (const float4*)A + (size_t)b * IND * NQ;
    const float* __restrict__ w1 = P1 + c * IND;
    const float* __restrict__ w2 = P2 + c * IND;
    const float* __restrict__ w3 = kw + c * IND;

    float a1[4] = {0.f, 0.f, 0.f, 0.f};
    float vv[4] = {0.f, 0.f, 0.f, 0.f};
    float kv[4] = {0.f, 0.f, 0.f, 0.f};

    #pragma unroll
    for (int blk = 0; blk < 16; ++blk) {
        float4 cur[8];
        #pragma unroll
        for (int j = 0; j < 8; ++j)
            cur[j] = A4[(blk * 8 + j) * NQ + x];     // 8 loads in flight
        #pragma unroll
        for (int j = 0; j < 8; ++j) {
            const int i = blk * 8 + j;
            const float wa = w1[i], wb = w2[i], wc = w3[i];  // uniform -> SGPR
            a1[0] = fmaf(wa, cur[j].x, a1[0]); a1[1] = fmaf(wa, cur[j].y, a1[1]);
            a1[2] = fmaf(wa, cur[j].z, a1[2]); a1[3] = fmaf(wa, cur[j].w, a1[3]);
            vv[0] = fmaf(wb, cur[j].x, vv[0]); vv[1] = fmaf(wb, cur[j].y, vv[1]);
            vv[2] = fmaf(wb, cur[j].z, vv[2]); vv[3] = fmaf(wb, cur[j].w, vv[3]);
            kv[0] = fmaf(wc, cur[j].x, kv[0]); kv[1] = fmaf(wc, cur[j].y, kv[1]);
            kv[2] = fmaf(wc, cur[j].z, kv[2]); kv[3] = fmaf(wc, cur[j].w, kv[3]);
        }
    }

    // S2 = sum_n kv^2, SV = sum_n |kv|*vv : full-n reduction within the wave.
    float s2 = 0.f, sv = 0.f;
    #pragma unroll
    for (int j = 0; j < 4; ++j) {
        s2 = fmaf(kv[j], kv[j], s2);
        sv = fmaf(fabsf(kv[j]), vv[j], sv);
    }
    #pragma unroll
    for (int off = 32; off >= 1; off >>= 1) {
        s2 += __shfl_xor(s2, off, 64);
        sv += __shfl_xor(sv, off, 64);
    }
    const float y = sv / sqrtf(s2);   // Y independent of i; Q cancels entirely.

    float p[4];
    float bnsum = 0.f, bnsq = 0.f;
    #pragma unroll
    for (int j = 0; j < 4; ++j) {
        float t = a1[j] + vv[j] + 0.1f * y;
        t = fmaxf(t, 0.f);            // ReLU
        p[j] = t;
        bnsum += t;
        bnsq  = fmaf(t, t, bnsq);
    }
    #pragma unroll
    for (int off = 32; off >= 1; off >>= 1) {
        bnsum += __shfl_xor(bnsum, off, 64);
        bnsq  += __shfl_xor(bnsq,  off, 64);
    }

    float4* __restrict__ p4 = (float4*)pbuf;
    p4[((size_t)b * OUTD + c) * NQ + x] = make_float4(p[0], p[1], p[2], p[3]);
    if (x == 0) {
        bnp[c * BB + b]              = bnsum;
        bnp[OUTD * BB + c * BB + b]  = bnsq;
    }
}

// ---------------- Kernel 2: BatchNorm combine + affine + store -------------
// Grid 128 (c), block (64, 8). Reads 8 partials per channel, normalizes.
__global__ __launch_bounds__(512) void k2_bn(
    const float* __restrict__ pbuf,  // [B, OUTD, NN]
    const float* __restrict__ bnp,   // [2][OUTD][BB]
    const float* __restrict__ gamma,
    const float* __restrict__ beta,
    float* __restrict__ out)         // [B, OUTD, NN]
{
    const int c = blockIdx.x;
    const int x = threadIdx.x;       // 0..63
    const int b = threadIdx.y;       // 0..7

    float tsum = 0.f, tsq = 0.f;
    #pragma unroll
    for (int w = 0; w < BB; ++w) {   // uniform addresses -> scalar loads
        tsum += bnp[c * BB + w];
        tsq  += bnp[OUTD * BB + c * BB + w];
    }
    const float inv   = 1.f / (float)(BB * NN);
    const float mean  = tsum * inv;
    const float var   = tsq * inv - mean * mean;     // biased var = jnp.var
    const float scale = gamma[c] * rsqrtf(var + BN_EPS);
    const float shift = beta[c] - mean * scale;

    const float4* __restrict__ p4 = (const float4*)pbuf;
    float4* __restrict__ out4 = (float4*)out;
    const size_t idx = ((size_t)b * OUTD + c) * NQ + x;
    const float4 p = p4[idx];
    out4[idx] = make_float4(fmaf(p.x, scale, shift), fmaf(p.y, scale, shift),
                            fmaf(p.z, scale, shift), fmaf(p.w, scale, shift));
}

extern "C" void kernel_launch(void* const* d_in, const int* in_sizes, int n_in,
                              void* d_out, int out_size, void* d_ws, size_t ws_size,
                              hipStream_t stream) {
    // setup_inputs order: A, P1, P2, q, k, gamma, beta, permutation_size1, BATCH_SIZE
    const float* A     = (const float*)d_in[0];
    const float* P1    = (const float*)d_in[1];
    const float* P2    = (const float*)d_in[2];
    // d_in[3] = q : unused (cancels in Alpha_norm)
    const float* kw    = (const float*)d_in[4];
    const float* gamma = (const float*)d_in[5];
    const float* beta  = (const float*)d_in[6];
    float* out = (float*)d_out;

    float* pbuf = (float*)d_ws;                                  // 1 MB
    float* bnp  = (float*)((char*)d_ws + (size_t)BB * OUTD * NN * sizeof(float));

    dim3 g1(OUTD, BB);
    k1_proj<<<g1, 64, 0, stream>>>(A, P1, P2, kw, pbuf, bnp);
    dim3 b2(64, BB);
    k2_bn<<<OUTD, b2, 0, stream>>>(pbuf, bnp, gamma, beta, out);
}